// Round 22
// baseline (112.764 us; speedup 1.0000x reference)
//
#include <hip/hip_runtime.h>

#define BSZ 4096
#define D 1024
#define N2 8192
#define TEMPV 0.5f
// exp(x/T) = exp2(x * log2(e)/T)
#define EXPSCALE 2.8853900817779268f
#define NTB 32      // 8192 / 256 tiles per dim
#define NBLK_ALL 576
#define NRED 32

typedef __attribute__((ext_vector_type(4))) float f32x4;
typedef __attribute__((ext_vector_type(4))) int i32x4;
typedef __attribute__((ext_vector_type(8))) int i32x8;

// float (pre-scaled by 32) -> fp4 e2m1 code, nearest; code==bit pattern
__device__ inline unsigned int f2e2m1(float y) {
  const float a = fabsf(y);
  unsigned int c = (unsigned int)(a > 0.25f) + (unsigned int)(a > 0.75f) +
                   (unsigned int)(a > 1.25f) + (unsigned int)(a > 1.75f) +
                   (unsigned int)(a > 2.5f) + (unsigned int)(a > 3.5f) +
                   (unsigned int)(a > 5.0f);
  return c | ((__float_as_uint(y) >> 28) & 8u);
}

__device__ inline void gload16(const void* g, void* l) {
  __builtin_amdgcn_global_load_lds(
      (const __attribute__((address_space(1))) void*)g,
      (__attribute__((address_space(3))) void*)l, 16, 0, 0);
}

// ---------------- Kernel A: L2-normalize rows, emit fp4 reps + pos dot ------------------
__global__ __launch_bounds__(256) void knorm(const float* __restrict__ ei,
                                             const float* __restrict__ ej,
                                             unsigned char* __restrict__ reps4,
                                             float* __restrict__ pos,
                                             int* __restrict__ cnt) {
  const int r = blockIdx.x;
  const int t = threadIdx.x;
  if (r == 0 && t == 0) { cnt[0] = 0; cnt[1] = 0; }   // reset counters (every call)
  const float4 vi = ((const float4*)(ei + (size_t)r * D))[t];
  const float4 vj = ((const float4*)(ej + (size_t)r * D))[t];
  float ssi = vi.x * vi.x + vi.y * vi.y + vi.z * vi.z + vi.w * vi.w;
  float ssj = vj.x * vj.x + vj.y * vj.y + vj.z * vj.z + vj.w * vj.w;
  float sij = vi.x * vj.x + vi.y * vj.y + vi.z * vj.z + vi.w * vj.w;
#pragma unroll
  for (int o = 32; o > 0; o >>= 1) {
    ssi += __shfl_xor(ssi, o);
    ssj += __shfl_xor(ssj, o);
    sij += __shfl_xor(sij, o);
  }
  __shared__ float red[12];
  const int lane = t & 63, wid = t >> 6;
  if (lane == 0) { red[wid * 3] = ssi; red[wid * 3 + 1] = ssj; red[wid * 3 + 2] = sij; }
  __syncthreads();
  ssi = red[0] + red[3] + red[6] + red[9];
  ssj = red[1] + red[4] + red[7] + red[10];
  sij = red[2] + red[5] + red[8] + red[11];
  const float inv_i = rsqrtf(fmaxf(ssi, 1e-24f)) * 32.f;
  const float inv_j = rsqrtf(fmaxf(ssj, 1e-24f)) * 32.f;
  const unsigned int qi = f2e2m1(vi.x * inv_i) | (f2e2m1(vi.y * inv_i) << 4) |
                          (f2e2m1(vi.z * inv_i) << 8) | (f2e2m1(vi.w * inv_i) << 12);
  const unsigned int qj = f2e2m1(vj.x * inv_j) | (f2e2m1(vj.y * inv_j) << 4) |
                          (f2e2m1(vj.z * inv_j) << 8) | (f2e2m1(vj.w * inv_j) << 12);
  *(unsigned short*)(reps4 + (size_t)r * 512 + t * 2) = (unsigned short)qi;
  *(unsigned short*)(reps4 + (size_t)(BSZ + r) * 512 + t * 2) = (unsigned short)qj;
  if (t == 0) pos[r] = sij * inv_i * inv_j * (1.f / 1024.f);
}

// ======================= shared asm helpers =======================
#define BARRIER() do { __builtin_amdgcn_s_barrier(); asm volatile("" ::: "memory"); } while (0)
#define STR2(x) #x
#define WAITV(n) asm volatile("s_waitcnt vmcnt(" STR2(n) ")" ::: "memory")

// ---------------- Kernel B: fp4 tails (0..63) + fp4 mains (64..575) + fused reduction ---
#define SG_A(ii, ktv, dst) gload16(reps4 + (size_t)(arow0 + (ii) * 128 + (t >> 2)) * 512 + \
                                       (ktv) * 64 + (((t & 3) ^ ((t >> 3) & 3)) << 4),     \
                                   (dst) + (size_t)(ii) * 8192 + (size_t)t * 16)
#define SG_B(ii, ktv, dst) gload16(reps4 + (size_t)(brow0 + (ii) * 128 + (t >> 2)) * 512 + \
                                       (ktv) * 64 + (((t & 3) ^ ((t >> 3) & 3)) << 4),     \
                                   (dst) + (size_t)(ii) * 8192 + (size_t)t * 16)

#define ABUF(c) ((c) ? 16384 : 0)
#define BBUF(c) ((c) ? 49152 : 32768)

#define READ_A2(bufoff, p) do {                                                       \
    i32x4 a0 = *(const i32x4*)(smem + (bufoff) + aaddr + ((p) * 2) * 1024);           \
    i32x4 a1 = *(const i32x4*)(smem + (bufoff) + aaddr + ((p) * 2 + 1) * 1024);       \
    afp[0] = __builtin_shufflevector(a0, a0, 0, 1, 2, 3, 0, 1, 2, 3);                 \
    afp[1] = __builtin_shufflevector(a1, a1, 0, 1, 2, 3, 0, 1, 2, 3);                 \
  } while (0)

#define READ_B2(bufoff, n) do {                                                       \
    i32x4 b0 = *(const i32x4*)(smem + (bufoff) + baddr + (n) * 1024);                 \
    bfp[n] = __builtin_shufflevector(b0, b0, 0, 1, 2, 3, 0, 1, 2, 3);                 \
  } while (0)

#define MFMA_P(p)                                                       \
  __builtin_amdgcn_s_setprio(1);                                        \
  _Pragma("unroll") for (int nh = 0; nh < 2; nh++)                      \
  _Pragma("unroll") for (int m2 = 0; m2 < 2; m2++)                      \
  _Pragma("unroll") for (int nn = 0; nn < 2; nn++) {                    \
    const int n_ = nh * 2 + nn;                                         \
    acc[2 * (p) + m2][n_] = __builtin_amdgcn_mfma_scale_f32_16x16x128_f8f6f4( \
        afp[m2], bfp[n_], acc[2 * (p) + m2][n_],                        \
        4, 4, 0, 0x7A7A7A7A, 0, 0x7A7A7A7A);                            \
  }                                                                     \
  __builtin_amdgcn_s_setprio(0);

#define DO_TILE(ktv, SA, SB, RDN, HASW, WV)                             \
  {                                                                     \
    READ_B2(BBUF((ktv) & 1), 2); READ_B2(BBUF((ktv) & 1), 3);           \
    MFMA_P(0);                                                          \
    READ_A2(ABUF((ktv) & 1), 1);                                        \
    if (SA) { SG_A(0, (ktv) + 1, smem + ABUF(((ktv) + 1) & 1));         \
              SG_A(1, (ktv) + 1, smem + ABUF(((ktv) + 1) & 1)); }       \
    BARRIER();                                                          \
    MFMA_P(1);                                                          \
    READ_A2(ABUF((ktv) & 1), 2);                                        \
    BARRIER();                                                          \
    MFMA_P(2);                                                          \
    READ_A2(ABUF((ktv) & 1), 3);                                        \
    if (SB) { SG_B(0, (ktv) + 2, smem + BBUF((ktv) & 1));               \
              SG_B(1, (ktv) + 2, smem + BBUF((ktv) & 1)); }             \
    if (HASW) { WAITV(WV); }                                            \
    BARRIER();                                                          \
    MFMA_P(3);                                                          \
    if (RDN) { READ_A2(ABUF(((ktv) + 1) & 1), 0);                       \
               READ_B2(BBUF(((ktv) + 1) & 1), 0);                       \
               READ_B2(BBUF(((ktv) + 1) & 1), 1); }                     \
    BARRIER();                                                          \
  }

// -------- tail-path macros (MX-fp4, 128x128 quarter-tile, BK=128) --------
#define TABUF(c) ((c) ? 8192 : 0)
#define TBBUF(c) ((c) ? 24576 : 16384)

#define TSG_A(ktv, dstoff) gload16(reps4 + (size_t)(tarow0 + (t >> 2)) * 512 + \
                                       (ktv) * 64 + (((t & 3) ^ ((t >> 3) & 3)) << 4), \
                                   smem + (dstoff) + (size_t)t * 16)
#define TSG_B(ktv, dstoff) gload16(reps4 + (size_t)(tbrow0 + (t >> 2)) * 512 + \
                                       (ktv) * 64 + (((t & 3) ^ ((t >> 3) & 3)) << 4), \
                                   smem + (dstoff) + (size_t)t * 16)

#define READ_TA(bufoff, m, dst) do {                                                  \
    i32x4 a0 = *(const i32x4*)(smem + (bufoff) + taaddr + (m) * 1024);                \
    dst = __builtin_shufflevector(a0, a0, 0, 1, 2, 3, 0, 1, 2, 3);                    \
  } while (0)

#define READ_TB(bufoff, n) do {                                                       \
    i32x4 b0 = *(const i32x4*)(smem + (bufoff) + tbaddr + (n) * 1024);                \
    tbfp[n] = __builtin_shufflevector(b0, b0, 0, 1, 2, 3, 0, 1, 2, 3);                \
  } while (0)

#define TMFMA(m, areg)                                                  \
  __builtin_amdgcn_s_setprio(1);                                        \
  _Pragma("unroll") for (int n_ = 0; n_ < 2; n_++)                      \
    tacc[m][n_] = __builtin_amdgcn_mfma_scale_f32_16x16x128_f8f6f4(     \
        areg, tbfp[n_], tacc[m][n_], 4, 4, 0, 0x7A7A7A7A, 0, 0x7A7A7A7A); \
  __builtin_amdgcn_s_setprio(0);

#define TTILE(ktv, SA, SB, RDN, HASW, WV)                               \
  {                                                                     \
    READ_TB(TBBUF((ktv) & 1), 1);                                       \
    TMFMA(0, tafp[0]);                                                  \
    READ_TA(TABUF((ktv) & 1), 1, tafp[1]);                              \
    if (SA) TSG_A((ktv) + 1, TABUF(((ktv) + 1) & 1));                   \
    BARRIER();                                                          \
    TMFMA(1, tafp[1]);                                                  \
    READ_TA(TABUF((ktv) & 1), 2, tafp[0]);                              \
    BARRIER();                                                          \
    TMFMA(2, tafp[0]);                                                  \
    READ_TA(TABUF((ktv) & 1), 3, tafp[1]);                              \
    if (SB) TSG_B((ktv) + 2, TBBUF((ktv) & 1));                         \
    if (HASW) { WAITV(WV); }                                            \
    BARRIER();                                                          \
    TMFMA(3, tafp[1]);                                                  \
    if (RDN) { READ_TA(TABUF(((ktv) + 1) & 1), 0, tafp[0]);             \
               READ_TB(TBBUF(((ktv) + 1) & 1), 0); }                    \
    BARRIER();                                                          \
  }

// 512-thread block reduce (waves contribute via LDS)
__device__ inline float blockReduce512(float v, float* sred) {
#pragma unroll
  for (int o = 32; o > 0; o >>= 1) v += __shfl_xor(v, o);
  const int lane = threadIdx.x & 63, wid = threadIdx.x >> 6;
  if (lane == 0) sred[wid] = v;
  __syncthreads();
  v = sred[0] + sred[1] + sred[2] + sred[3] + sred[4] + sred[5] + sred[6] + sred[7];
  __syncthreads();
  return v;
}

__global__ __launch_bounds__(512, 1) void kgemm3(const unsigned char* __restrict__ reps4,
                                                 float* __restrict__ partial,
                                                 const float* __restrict__ pos,
                                                 float* __restrict__ bsum,
                                                 int* __restrict__ cnt,
                                                 float* __restrict__ out) {
  extern __shared__ char smem[];
  const int t = threadIdx.x;
  const int l = t & 63, w = t >> 6;
  const int wr = w >> 2, wc = w & 3;          // 2 x 4 wave grid
  const int q2 = (l >> 4) & 3;
  const int lswz = ((l & 15) >> 1) & 3;       // == (row>>1)&3 for all row bases used
  const int off4 = ((q2 ^ lswz) << 4);

  if (blockIdx.x < 64) {
    // ===== tail path (fp4): 128x128 quarter-tiles of excluded tiles (0, 16..31) =======
    const int b = (int)blockIdx.x;              // 0..63
    const int s = b >> 2, quad = b & 3;
    const int qr = quad >> 1, qc = quad & 1;
    const int cbt = 16 + s;

    f32x4 tacc[4][2];
    const f32x4 zero4t = {0.f, 0.f, 0.f, 0.f};
#pragma unroll
    for (int m = 0; m < 4; m++)
#pragma unroll
      for (int n = 0; n < 2; n++) tacc[m][n] = zero4t;

    const size_t tarow0 = (size_t)qr * 128;                     // rows 0..255
    const size_t tbrow0 = (size_t)cbt * 256 + (size_t)qc * 128; // cols >= 4096
    const int taaddr = (wr * 64 + (l & 15)) * 64 + off4;        // + m*1024
    const int tbaddr = (wc * 32 + (l & 15)) * 64 + off4;        // + n*1024

    TSG_B(0, 16384);
    TSG_A(0, 0);
    TSG_B(1, 24576);
    WAITV(1);
    BARRIER();

    i32x8 tafp[2], tbfp[2];
    READ_TA(0, 0, tafp[0]);
    READ_TB(16384, 0);

    TTILE(0, 1, 1, 1, 1, 1)
    TTILE(1, 1, 1, 1, 1, 1)
    TTILE(2, 1, 1, 1, 1, 1)
    TTILE(3, 1, 1, 1, 1, 1)
    TTILE(4, 1, 1, 1, 1, 1)
    TTILE(5, 1, 1, 1, 1, 1)
    TTILE(6, 1, 0, 1, 1, 0)
    TTILE(7, 0, 0, 0, 0, 0)

    float rsum[4][4];
    float csum[2];
#pragma unroll
    for (int m = 0; m < 4; m++)
#pragma unroll
      for (int j = 0; j < 4; j++) rsum[m][j] = 0.f;
    csum[0] = 0.f; csum[1] = 0.f;

#pragma unroll
    for (int m = 0; m < 4; m++)
#pragma unroll
      for (int n = 0; n < 2; n++)
#pragma unroll
        for (int j = 0; j < 4; j++) {
          const float e = exp2f(tacc[m][n][j] * EXPSCALE);
          rsum[m][j] += e;
          csum[n] += e;
        }
#pragma unroll
    for (int m = 0; m < 4; m++)
#pragma unroll
      for (int j = 0; j < 4; j++) {
        float v = rsum[m][j];
        v += __shfl_xor(v, 1); v += __shfl_xor(v, 2);
        v += __shfl_xor(v, 4); v += __shfl_xor(v, 8);
        rsum[m][j] = v;
      }
#pragma unroll
    for (int n = 0; n < 2; n++) {
      float v = csum[n];
      v += __shfl_xor(v, 16); v += __shfl_xor(v, 32);
      csum[n] = v;
    }

    const int col16 = l & 15, rgp = (l >> 4) & 3;
    __syncthreads();
    float* rS = (float*)smem;            // [4 wc][128 rows]
    float* cS = ((float*)smem) + 512;    // [2 wr][128 cols]
    if (col16 == 0) {
#pragma unroll
      for (int m = 0; m < 4; m++)
#pragma unroll
        for (int j = 0; j < 4; j++)
          rS[wc * 128 + wr * 64 + m * 16 + rgp * 4 + j] = rsum[m][j];
    }
    if (rgp == 0) {
#pragma unroll
      for (int n = 0; n < 2; n++)
        cS[wr * 128 + wc * 32 + n * 16 + col16] = csum[n];
    }
    __syncthreads();
    if (t < 128) {
      const float rs = rS[t] + rS[128 + t] + rS[256 + t] + rS[384 + t];
      partial[(size_t)(cbt * 2 + qc) * N2 + qr * 128 + t] = rs;
      const float cs = cS[t] + cS[128 + t];
      partial[(size_t)(64 + qr) * N2 + cbt * 256 + qc * 128 + t] = cs;
    }
  } else {
    // ================= main path: 256x256 MX-fp4 tiles (R21 verbatim) ================
    int bid = (int)blockIdx.x - 64;
    bid = (bid & 7) * 64 + (bid >> 3);   // XCD swizzle (512 = 8*64, bijective)
    int rb, cb;
    if (bid < 16) {
      rb = 0; cb = bid;
    } else {
      int rem = bid - 16;
      rb = 1;
      while (rem >= NTB - rb) { rem -= NTB - rb; rb++; }
      cb = rb + rem;
    }

    f32x4 acc[8][4];
    const f32x4 zero4 = {0.f, 0.f, 0.f, 0.f};
#pragma unroll
    for (int m = 0; m < 8; m++)
#pragma unroll
      for (int n = 0; n < 4; n++) acc[m][n] = zero4;

    const size_t arow0 = (size_t)rb * 256;
    const size_t brow0 = (size_t)cb * 256;

    const int arow = wr * 128 + (l & 15);
    const int brow = wc * 64 + (l & 15);
    const int aaddr = arow * 64 + off4;
    const int baddr = brow * 64 + off4;

    SG_B(0, 0, smem + 32768); SG_B(1, 0, smem + 32768);
    SG_A(0, 0, smem); SG_A(1, 0, smem);
    SG_B(0, 1, smem + 49152); SG_B(1, 1, smem + 49152);
    WAITV(2);
    BARRIER();

    i32x8 afp[2], bfp[4];
    READ_A2(0, 0);
    READ_B2(32768, 0);
    READ_B2(32768, 1);

    DO_TILE(0, 1, 1, 1, 1, 2)
    DO_TILE(1, 1, 1, 1, 1, 2)
    DO_TILE(2, 1, 1, 1, 1, 2)
    DO_TILE(3, 1, 1, 1, 1, 2)
    DO_TILE(4, 1, 1, 1, 1, 2)
    DO_TILE(5, 1, 1, 1, 1, 2)
    DO_TILE(6, 1, 0, 1, 1, 0)
    DO_TILE(7, 0, 0, 0, 0, 0)

    float rsum[8][4];
    float csum[4];
#pragma unroll
    for (int m = 0; m < 8; m++)
#pragma unroll
      for (int j = 0; j < 4; j++) rsum[m][j] = 0.f;
#pragma unroll
    for (int n = 0; n < 4; n++) csum[n] = 0.f;

    const int col16 = l & 15, rgp = (l >> 4) & 3;
    const bool diag = (rb == cb);
    const int growbase = wr * 128 + rgp * 4;
    const int gcolbase = wc * 64 + col16;
#pragma unroll
    for (int m = 0; m < 8; m++) {
#pragma unroll
      for (int n = 0; n < 4; n++) {
#pragma unroll
        for (int j = 0; j < 4; j++) {
          const float e = (diag && (growbase + m * 16 + j) == (gcolbase + n * 16))
                              ? 0.f
                              : exp2f(acc[m][n][j] * EXPSCALE);
          rsum[m][j] += e;
          csum[n] += e;
        }
      }
    }
#pragma unroll
    for (int m = 0; m < 8; m++)
#pragma unroll
      for (int j = 0; j < 4; j++) {
        float v = rsum[m][j];
        v += __shfl_xor(v, 1); v += __shfl_xor(v, 2);
        v += __shfl_xor(v, 4); v += __shfl_xor(v, 8);
        rsum[m][j] = v;
      }
#pragma unroll
    for (int n = 0; n < 4; n++) {
      float v = csum[n];
      v += __shfl_xor(v, 16); v += __shfl_xor(v, 32);
      csum[n] = v;
    }

    __syncthreads();
    float* rS = (float*)smem;            // [4 wc][256 rows]
    float* cS = ((float*)smem) + 1024;   // [2 wr][256 cols]
    if (col16 == 0) {
#pragma unroll
      for (int m = 0; m < 8; m++)
#pragma unroll
        for (int j = 0; j < 4; j++)
          rS[wc * 256 + wr * 128 + m * 16 + rgp * 4 + j] = rsum[m][j];
    }
    if (rgp == 0) {
#pragma unroll
      for (int n = 0; n < 4; n++)
        cS[wr * 256 + wc * 64 + n * 16 + col16] = csum[n];
    }
    __syncthreads();
    // partial layout: [66 col-blocks of 128][8192 rows]
    if (t < 256) {
      const float rs_lo = rS[t] + rS[256 + t];
      const float rs_hi = rS[512 + t] + rS[768 + t];
      partial[(size_t)(cb * 2) * N2 + rb * 256 + t] = rs_lo;
      partial[(size_t)(cb * 2 + 1) * N2 + rb * 256 + t] = rs_hi;
      if (!diag) {
        partial[(size_t)(rb * 2) * N2 + cb * 256 + t] = cS[t];
        partial[(size_t)(rb * 2 + 1) * N2 + cb * 256 + t] = cS[256 + t];
      }
    }
  }

  // ============ fused reduction: last NRED ticket-holders reduce 256 rows each ==========
  __shared__ int ticket_s;
  __shared__ int lastFlag;
  __syncthreads();                        // all partial stores issued block-wide
  if (t == 0) {
    __threadfence();                      // make partial stores device-visible
    ticket_s = atomicAdd(cnt, 1);
  }
  __syncthreads();
  const int ticket = ticket_s;
  if (ticket < NBLK_ALL - NRED) return;
  if (t == 0) {
    while (atomicAdd(cnt, 0) < NBLK_ALL) __builtin_amdgcn_s_sleep(8);
  }
  __syncthreads();
  __threadfence();                        // acquire before reading others' partials
  const int chunk = ticket - (NBLK_ALL - NRED);   // 0..31
  float v = 0.f;
  if (t < 256) {
    const int rr = chunk * 256 + t;
    float d = 0.f;
#pragma unroll 8
    for (int cbx = 0; cbx < 64; ++cbx) d += partial[(size_t)cbx * N2 + rr];
    if (chunk >= 16) {                    // rows >= 4096: tail colsum slots 64..65
      d += partial[(size_t)64 * N2 + rr];
      d += partial[(size_t)65 * N2 + rr];
    }
    v = logf(d);
  }
  float* sred = (float*)smem;
  __syncthreads();
  v = blockReduce512(v, sred);
  if (t == 0) {
    bsum[chunk] = v;
    __threadfence();
    lastFlag = (atomicAdd(cnt + 1, 1) == NRED - 1);
  }
  __syncthreads();
  if (!lastFlag) return;
  __threadfence();
  float s = (t < NRED) ? ((volatile float*)bsum)[t] : 0.f;
  float p = 0.f;
  for (int k = t; k < BSZ; k += 512) p += pos[k];
  s = blockReduce512(s, sred);
  p = blockReduce512(p, sred);
  if (t == 0) out[0] = (s - 2.0f * p / TEMPV) / (float)N2;
}

extern "C" void kernel_launch(void* const* d_in, const int* in_sizes, int n_in,
                              void* d_out, int out_size, void* d_ws, size_t ws_size,
                              hipStream_t stream) {
  const float* ei = (const float*)d_in[0];
  const float* ej = (const float*)d_in[1];
  char* ws = (char*)d_ws;
  unsigned char* reps4 = (unsigned char*)ws;                           // 4 MB fp4 [8192][512]
  float* partial = (float*)(ws + (size_t)4 * 1024 * 1024);             // 2.06 MB [66][8192]
  float* pos = (float*)(ws + (size_t)4 * 1024 * 1024 + 2176 * 1024);   // 16 KB [4096]
  float* bsum = (float*)(ws + (size_t)4 * 1024 * 1024 + 2176 * 1024 + 16384); // 128 B
  int* cnt = (int*)(ws + (size_t)4 * 1024 * 1024 + 2176 * 1024 + 16384 + 256);

  (void)hipFuncSetAttribute((const void*)kgemm3,
                            hipFuncAttributeMaxDynamicSharedMemorySize, 65536);

  knorm<<<BSZ, 256, 0, stream>>>(ei, ej, reps4, pos, cnt);
  kgemm3<<<NBLK_ALL, 512, 65536, stream>>>(reps4, partial, pos, bsum, cnt, (float*)d_out);
}

// Round 23
// 58.805 us; speedup vs baseline: 1.9176x; 1.9176x over previous
//
#include <hip/hip_runtime.h>

#define BSZ 4096
#define D 1024
#define N2 8192
#define TEMPV 0.5f
// exp(x/T) = exp2(x * log2(e)/T)
#define EXPSCALE 2.8853900817779268f
#define NTB 32      // 8192 / 256 tiles per dim

typedef __attribute__((ext_vector_type(4))) float f32x4;
typedef __attribute__((ext_vector_type(4))) int i32x4;
typedef __attribute__((ext_vector_type(8))) int i32x8;

// float (pre-scaled by 32) -> fp4 e2m1 code, nearest; code==bit pattern
__device__ inline unsigned int f2e2m1(float y) {
  const float a = fabsf(y);
  unsigned int c = (unsigned int)(a > 0.25f) + (unsigned int)(a > 0.75f) +
                   (unsigned int)(a > 1.25f) + (unsigned int)(a > 1.75f) +
                   (unsigned int)(a > 2.5f) + (unsigned int)(a > 3.5f) +
                   (unsigned int)(a > 5.0f);
  return c | ((__float_as_uint(y) >> 28) & 8u);
}

__device__ inline void gload16(const void* g, void* l) {
  __builtin_amdgcn_global_load_lds(
      (const __attribute__((address_space(1))) void*)g,
      (__attribute__((address_space(3))) void*)l, 16, 0, 0);
}

// ---------------- Kernel A: L2-normalize rows, emit fp4 reps + pos dot ------------------
__global__ __launch_bounds__(256) void knorm(const float* __restrict__ ei,
                                             const float* __restrict__ ej,
                                             unsigned char* __restrict__ reps4,
                                             float* __restrict__ pos,
                                             int* __restrict__ cnt) {
  const int r = blockIdx.x;
  const int t = threadIdx.x;
  if (r == 0 && t == 0) *cnt = 0;   // reset done-counter for fused kred (every call)
  const float4 vi = ((const float4*)(ei + (size_t)r * D))[t];
  const float4 vj = ((const float4*)(ej + (size_t)r * D))[t];
  float ssi = vi.x * vi.x + vi.y * vi.y + vi.z * vi.z + vi.w * vi.w;
  float ssj = vj.x * vj.x + vj.y * vj.y + vj.z * vj.z + vj.w * vj.w;
  float sij = vi.x * vj.x + vi.y * vj.y + vi.z * vj.z + vi.w * vj.w;
#pragma unroll
  for (int o = 32; o > 0; o >>= 1) {
    ssi += __shfl_xor(ssi, o);
    ssj += __shfl_xor(ssj, o);
    sij += __shfl_xor(sij, o);
  }
  __shared__ float red[12];
  const int lane = t & 63, wid = t >> 6;
  if (lane == 0) { red[wid * 3] = ssi; red[wid * 3 + 1] = ssj; red[wid * 3 + 2] = sij; }
  __syncthreads();
  ssi = red[0] + red[3] + red[6] + red[9];
  ssj = red[1] + red[4] + red[7] + red[10];
  sij = red[2] + red[5] + red[8] + red[11];
  const float inv_i = rsqrtf(fmaxf(ssi, 1e-24f)) * 32.f;
  const float inv_j = rsqrtf(fmaxf(ssj, 1e-24f)) * 32.f;
  const unsigned int qi = f2e2m1(vi.x * inv_i) | (f2e2m1(vi.y * inv_i) << 4) |
                          (f2e2m1(vi.z * inv_i) << 8) | (f2e2m1(vi.w * inv_i) << 12);
  const unsigned int qj = f2e2m1(vj.x * inv_j) | (f2e2m1(vj.y * inv_j) << 4) |
                          (f2e2m1(vj.z * inv_j) << 8) | (f2e2m1(vj.w * inv_j) << 12);
  *(unsigned short*)(reps4 + (size_t)r * 512 + t * 2) = (unsigned short)qi;
  *(unsigned short*)(reps4 + (size_t)(BSZ + r) * 512 + t * 2) = (unsigned short)qj;
  if (t == 0) pos[r] = sij * inv_i * inv_j * (1.f / 1024.f);
}

// ======================= shared asm helpers =======================
#define BARRIER() do { __builtin_amdgcn_s_barrier(); asm volatile("" ::: "memory"); } while (0)
#define STR2(x) #x
#define WAITV(n) asm volatile("s_waitcnt vmcnt(" STR2(n) ")" ::: "memory")

// ---------------- Kernel B (merged): fp4 tails FIRST (0..63), fp4 mains (64..575) -------
// Main: 256x256 MX-fp4 tile, BK=128 (rows = 64B), 8 waves (2Mx4N), wave tile 128x64.
// LDS: A dbuf @0/@16384, B dbuf @32768/@49152. Swizzle: 16B chunk c at c ^ ((row>>1)&3).
// fp4 operand = one b128/lane DUPLICATED into both operand halves (FMT=4-safe).
// Scales 0x7A = 2^-5 on both sides (values pre-scaled by 32). R20 ledger.
#define SG_A(ii, ktv, dst) gload16(reps4 + (size_t)(arow0 + (ii) * 128 + (t >> 2)) * 512 + \
                                       (ktv) * 64 + (((t & 3) ^ ((t >> 3) & 3)) << 4),     \
                                   (dst) + (size_t)(ii) * 8192 + (size_t)t * 16)
#define SG_B(ii, ktv, dst) gload16(reps4 + (size_t)(brow0 + (ii) * 128 + (t >> 2)) * 512 + \
                                       (ktv) * 64 + (((t & 3) ^ ((t >> 3) & 3)) << 4),     \
                                   (dst) + (size_t)(ii) * 8192 + (size_t)t * 16)

#define ABUF(c) ((c) ? 16384 : 0)
#define BBUF(c) ((c) ? 49152 : 32768)

#define READ_A2(bufoff, p) do {                                                       \
    i32x4 a0 = *(const i32x4*)(smem + (bufoff) + aaddr + ((p) * 2) * 1024);           \
    i32x4 a1 = *(const i32x4*)(smem + (bufoff) + aaddr + ((p) * 2 + 1) * 1024);       \
    afp[0] = __builtin_shufflevector(a0, a0, 0, 1, 2, 3, 0, 1, 2, 3);                 \
    afp[1] = __builtin_shufflevector(a1, a1, 0, 1, 2, 3, 0, 1, 2, 3);                 \
  } while (0)

#define READ_B2(bufoff, n) do {                                                       \
    i32x4 b0 = *(const i32x4*)(smem + (bufoff) + baddr + (n) * 1024);                 \
    bfp[n] = __builtin_shufflevector(b0, b0, 0, 1, 2, 3, 0, 1, 2, 3);                 \
  } while (0)

#define MFMA_P(p)                                                       \
  __builtin_amdgcn_s_setprio(1);                                        \
  _Pragma("unroll") for (int nh = 0; nh < 2; nh++)                      \
  _Pragma("unroll") for (int m2 = 0; m2 < 2; m2++)                      \
  _Pragma("unroll") for (int nn = 0; nn < 2; nn++) {                    \
    const int n_ = nh * 2 + nn;                                         \
    acc[2 * (p) + m2][n_] = __builtin_amdgcn_mfma_scale_f32_16x16x128_f8f6f4( \
        afp[m2], bfp[n_], acc[2 * (p) + m2][n_],                        \
        4, 4, 0, 0x7A7A7A7A, 0, 0x7A7A7A7A);                            \
  }                                                                     \
  __builtin_amdgcn_s_setprio(0);

#define DO_TILE(ktv, SA, SB, RDN, HASW, WV)                             \
  {                                                                     \
    READ_B2(BBUF((ktv) & 1), 2); READ_B2(BBUF((ktv) & 1), 3);           \
    MFMA_P(0);                                                          \
    READ_A2(ABUF((ktv) & 1), 1);                                        \
    if (SA) { SG_A(0, (ktv) + 1, smem + ABUF(((ktv) + 1) & 1));         \
              SG_A(1, (ktv) + 1, smem + ABUF(((ktv) + 1) & 1)); }       \
    BARRIER();                                                          \
    MFMA_P(1);                                                          \
    READ_A2(ABUF((ktv) & 1), 2);                                        \
    BARRIER();                                                          \
    MFMA_P(2);                                                          \
    READ_A2(ABUF((ktv) & 1), 3);                                        \
    if (SB) { SG_B(0, (ktv) + 2, smem + BBUF((ktv) & 1));               \
              SG_B(1, (ktv) + 2, smem + BBUF((ktv) & 1)); }             \
    if (HASW) { WAITV(WV); }                                            \
    BARRIER();                                                          \
    MFMA_P(3);                                                          \
    if (RDN) { READ_A2(ABUF(((ktv) + 1) & 1), 0);                       \
               READ_B2(BBUF(((ktv) + 1) & 1), 0);                       \
               READ_B2(BBUF(((ktv) + 1) & 1), 1); }                     \
    BARRIER();                                                          \
  }

// -------- tail-path macros (MX-fp4, 128x128 quarter-tile, BK=128) --------
// LDS: A dbuf @0/@8192, B dbuf @16384/@24576 (8 KB each = 128 rows x 64 B).
// Per-thread ledger: 1 SG_A@ph1(t+1), 1 SG_B@ph3(t+2); WAITV(1)@ph3 retires
// B(t+1)+A(t+1); t6 WAITV(0); prologue B(0),A(0),B(1) + WAITV(1).
#define TABUF(c) ((c) ? 8192 : 0)
#define TBBUF(c) ((c) ? 24576 : 16384)

#define TSG_A(ktv, dstoff) gload16(reps4 + (size_t)(tarow0 + (t >> 2)) * 512 + \
                                       (ktv) * 64 + (((t & 3) ^ ((t >> 3) & 3)) << 4), \
                                   smem + (dstoff) + (size_t)t * 16)
#define TSG_B(ktv, dstoff) gload16(reps4 + (size_t)(tbrow0 + (t >> 2)) * 512 + \
                                       (ktv) * 64 + (((t & 3) ^ ((t >> 3) & 3)) << 4), \
                                   smem + (dstoff) + (size_t)t * 16)

#define READ_TA(bufoff, m, dst) do {                                                  \
    i32x4 a0 = *(const i32x4*)(smem + (bufoff) + taaddr + (m) * 1024);                \
    dst = __builtin_shufflevector(a0, a0, 0, 1, 2, 3, 0, 1, 2, 3);                    \
  } while (0)

#define READ_TB(bufoff, n) do {                                                       \
    i32x4 b0 = *(const i32x4*)(smem + (bufoff) + tbaddr + (n) * 1024);                \
    tbfp[n] = __builtin_shufflevector(b0, b0, 0, 1, 2, 3, 0, 1, 2, 3);                \
  } while (0)

#define TMFMA(m, areg)                                                  \
  __builtin_amdgcn_s_setprio(1);                                        \
  _Pragma("unroll") for (int n_ = 0; n_ < 2; n_++)                      \
    tacc[m][n_] = __builtin_amdgcn_mfma_scale_f32_16x16x128_f8f6f4(     \
        areg, tbfp[n_], tacc[m][n_], 4, 4, 0, 0x7A7A7A7A, 0, 0x7A7A7A7A); \
  __builtin_amdgcn_s_setprio(0);

#define TTILE(ktv, SA, SB, RDN, HASW, WV)                               \
  {                                                                     \
    READ_TB(TBBUF((ktv) & 1), 1);                                       \
    TMFMA(0, tafp[0]);                                                  \
    READ_TA(TABUF((ktv) & 1), 1, tafp[1]);                              \
    if (SA) TSG_A((ktv) + 1, TABUF(((ktv) + 1) & 1));                   \
    BARRIER();                                                          \
    TMFMA(1, tafp[1]);                                                  \
    READ_TA(TABUF((ktv) & 1), 2, tafp[0]);                              \
    BARRIER();                                                          \
    TMFMA(2, tafp[0]);                                                  \
    READ_TA(TABUF((ktv) & 1), 3, tafp[1]);                              \
    if (SB) TSG_B((ktv) + 2, TBBUF((ktv) & 1));                         \
    if (HASW) { WAITV(WV); }                                            \
    BARRIER();                                                          \
    TMFMA(3, tafp[1]);                                                  \
    if (RDN) { READ_TA(TABUF(((ktv) + 1) & 1), 0, tafp[0]);             \
               READ_TB(TBBUF(((ktv) + 1) & 1), 0); }                    \
    BARRIER();                                                          \
  }

__global__ __launch_bounds__(512, 1) void kgemm3(const unsigned char* __restrict__ reps4,
                                                 float* __restrict__ partial) {
  extern __shared__ char smem[];
  const int t = threadIdx.x;
  const int l = t & 63, w = t >> 6;
  const int wr = w >> 2, wc = w & 3;          // 2 x 4 wave grid
  const int q2 = (l >> 4) & 3;
  const int lswz = ((l & 15) >> 1) & 3;       // == (row>>1)&3 for all row bases used
  const int off4 = ((q2 ^ lswz) << 4);

  if (blockIdx.x < 64) {
    // ===== tail path (fp4): 128x128 quarter-tiles of excluded tiles (0, 16..31) =======
    const int b = (int)blockIdx.x;              // 0..63
    const int s = b >> 2, quad = b & 3;
    const int qr = quad >> 1, qc = quad & 1;
    const int cbt = 16 + s;

    f32x4 tacc[4][2];
    const f32x4 zero4t = {0.f, 0.f, 0.f, 0.f};
#pragma unroll
    for (int m = 0; m < 4; m++)
#pragma unroll
      for (int n = 0; n < 2; n++) tacc[m][n] = zero4t;

    const size_t tarow0 = (size_t)qr * 128;                     // rows 0..255
    const size_t tbrow0 = (size_t)cbt * 256 + (size_t)qc * 128; // cols >= 4096
    const int taaddr = (wr * 64 + (l & 15)) * 64 + off4;        // + m*1024
    const int tbaddr = (wc * 32 + (l & 15)) * 64 + off4;        // + n*1024

    // prologue: B(0), A(0), B(1); retire B(0)+A(0); preload tile-0 ops
    TSG_B(0, 16384);
    TSG_A(0, 0);
    TSG_B(1, 24576);
    WAITV(1);
    BARRIER();

    i32x8 tafp[2], tbfp[2];
    READ_TA(0, 0, tafp[0]);
    READ_TB(16384, 0);

    TTILE(0, 1, 1, 1, 1, 1)
    TTILE(1, 1, 1, 1, 1, 1)
    TTILE(2, 1, 1, 1, 1, 1)
    TTILE(3, 1, 1, 1, 1, 1)
    TTILE(4, 1, 1, 1, 1, 1)
    TTILE(5, 1, 1, 1, 1, 1)
    TTILE(6, 1, 0, 1, 1, 0)
    TTILE(7, 0, 0, 0, 0, 0)

    // epilogue (no diagonal: rows < 256, cols >= 4096)
    float rsum[4][4];
    float csum[2];
#pragma unroll
    for (int m = 0; m < 4; m++)
#pragma unroll
      for (int j = 0; j < 4; j++) rsum[m][j] = 0.f;
    csum[0] = 0.f; csum[1] = 0.f;

#pragma unroll
    for (int m = 0; m < 4; m++)
#pragma unroll
      for (int n = 0; n < 2; n++)
#pragma unroll
        for (int j = 0; j < 4; j++) {
          const float e = exp2f(tacc[m][n][j] * EXPSCALE);
          rsum[m][j] += e;
          csum[n] += e;
        }
#pragma unroll
    for (int m = 0; m < 4; m++)
#pragma unroll
      for (int j = 0; j < 4; j++) {
        float v = rsum[m][j];
        v += __shfl_xor(v, 1); v += __shfl_xor(v, 2);
        v += __shfl_xor(v, 4); v += __shfl_xor(v, 8);
        rsum[m][j] = v;
      }
#pragma unroll
    for (int n = 0; n < 2; n++) {
      float v = csum[n];
      v += __shfl_xor(v, 16); v += __shfl_xor(v, 32);
      csum[n] = v;
    }

    const int col16 = l & 15, rgp = (l >> 4) & 3;
    __syncthreads();
    float* rS = (float*)smem;            // [4 wc][128 rows]
    float* cS = ((float*)smem) + 512;    // [2 wr][128 cols]
    if (col16 == 0) {
#pragma unroll
      for (int m = 0; m < 4; m++)
#pragma unroll
        for (int j = 0; j < 4; j++)
          rS[wc * 128 + wr * 64 + m * 16 + rgp * 4 + j] = rsum[m][j];
    }
    if (rgp == 0) {
#pragma unroll
      for (int n = 0; n < 2; n++)
        cS[wr * 128 + wc * 32 + n * 16 + col16] = csum[n];
    }
    __syncthreads();
    if (t < 128) {
      const float rs = rS[t] + rS[128 + t] + rS[256 + t] + rS[384 + t];
      partial[(size_t)(cbt * 2 + qc) * N2 + qr * 128 + t] = rs;
      const float cs = cS[t] + cS[128 + t];
      partial[(size_t)(64 + qr) * N2 + cbt * 256 + qc * 128 + t] = cs;
    }
    return;
  }

  // ================= main path: 256x256 MX-fp4 tiles (R20 verbatim) ==================
  int bid = (int)blockIdx.x - 64;
  bid = (bid & 7) * 64 + (bid >> 3);   // XCD swizzle (512 = 8*64, bijective)
  int rb, cb;
  if (bid < 16) {
    rb = 0; cb = bid;
  } else {
    int rem = bid - 16;
    rb = 1;
    while (rem >= NTB - rb) { rem -= NTB - rb; rb++; }
    cb = rb + rem;
  }

  f32x4 acc[8][4];
  const f32x4 zero4 = {0.f, 0.f, 0.f, 0.f};
#pragma unroll
  for (int m = 0; m < 8; m++)
#pragma unroll
    for (int n = 0; n < 4; n++) acc[m][n] = zero4;

  const size_t arow0 = (size_t)rb * 256;
  const size_t brow0 = (size_t)cb * 256;

  const int arow = wr * 128 + (l & 15);
  const int brow = wc * 64 + (l & 15);
  const int aaddr = arow * 64 + off4;
  const int baddr = brow * 64 + off4;

  // ---- prologue: B(0), A(0), B(1); retire B(0)+A(0); preload tile-0 ph1 ops ----
  SG_B(0, 0, smem + 32768); SG_B(1, 0, smem + 32768);
  SG_A(0, 0, smem); SG_A(1, 0, smem);
  SG_B(0, 1, smem + 49152); SG_B(1, 1, smem + 49152);
  WAITV(2);
  BARRIER();

  i32x8 afp[2], bfp[4];
  READ_A2(0, 0);
  READ_B2(32768, 0);
  READ_B2(32768, 1);

  DO_TILE(0, 1, 1, 1, 1, 2)
  DO_TILE(1, 1, 1, 1, 1, 2)
  DO_TILE(2, 1, 1, 1, 1, 2)
  DO_TILE(3, 1, 1, 1, 1, 2)
  DO_TILE(4, 1, 1, 1, 1, 2)
  DO_TILE(5, 1, 1, 1, 1, 2)
  DO_TILE(6, 1, 0, 1, 1, 0)
  DO_TILE(7, 0, 0, 0, 0, 0)

  // -------- epilogue: exp + diagonal mask + row/col partial sums --------
  float rsum[8][4];
  float csum[4];
#pragma unroll
  for (int m = 0; m < 8; m++)
#pragma unroll
    for (int j = 0; j < 4; j++) rsum[m][j] = 0.f;
#pragma unroll
  for (int n = 0; n < 4; n++) csum[n] = 0.f;

  const int col16 = l & 15, rgp = (l >> 4) & 3;
  const bool diag = (rb == cb);
  const int growbase = wr * 128 + rgp * 4;
  const int gcolbase = wc * 64 + col16;
#pragma unroll
  for (int m = 0; m < 8; m++) {
#pragma unroll
    for (int n = 0; n < 4; n++) {
#pragma unroll
      for (int j = 0; j < 4; j++) {
        const float e = (diag && (growbase + m * 16 + j) == (gcolbase + n * 16))
                            ? 0.f
                            : exp2f(acc[m][n][j] * EXPSCALE);
        rsum[m][j] += e;
        csum[n] += e;
      }
    }
  }
#pragma unroll
  for (int m = 0; m < 8; m++)
#pragma unroll
    for (int j = 0; j < 4; j++) {
      float v = rsum[m][j];
      v += __shfl_xor(v, 1); v += __shfl_xor(v, 2);
      v += __shfl_xor(v, 4); v += __shfl_xor(v, 8);
      rsum[m][j] = v;
    }
#pragma unroll
  for (int n = 0; n < 4; n++) {
    float v = csum[n];
    v += __shfl_xor(v, 16); v += __shfl_xor(v, 32);
    csum[n] = v;
  }

  __syncthreads();   // all waves done with LDS tiles before reuse as reduction scratch
  float* rS = (float*)smem;            // [4 wc][256 rows]
  float* cS = ((float*)smem) + 1024;   // [2 wr][256 cols]
  if (col16 == 0) {
#pragma unroll
    for (int m = 0; m < 8; m++)
#pragma unroll
      for (int j = 0; j < 4; j++)
        rS[wc * 256 + wr * 128 + m * 16 + rgp * 4 + j] = rsum[m][j];
  }
  if (rgp == 0) {
#pragma unroll
    for (int n = 0; n < 4; n++)
      cS[wr * 256 + wc * 64 + n * 16 + col16] = csum[n];
  }
  __syncthreads();
  // partial layout: [66 col-blocks of 128][8192 rows]
  if (t < 256) {
    const float rs_lo = rS[t] + rS[256 + t];
    const float rs_hi = rS[512 + t] + rS[768 + t];
    partial[(size_t)(cb * 2) * N2 + rb * 256 + t] = rs_lo;
    partial[(size_t)(cb * 2 + 1) * N2 + rb * 256 + t] = rs_hi;
    if (!diag) {
      partial[(size_t)(rb * 2) * N2 + cb * 256 + t] = cS[t];
      partial[(size_t)(rb * 2 + 1) * N2 + cb * 256 + t] = cS[256 + t];
    }
  }
}

// ---------------- Kernel C: per-row denom + fused final scalar (last-block) ---------------
__device__ inline float blockReduce(float v, float* sred) {
#pragma unroll
  for (int o = 32; o > 0; o >>= 1) v += __shfl_xor(v, o);
  const int lane = threadIdx.x & 63, wid = threadIdx.x >> 6;
  if (lane == 0) sred[wid] = v;
  __syncthreads();
  v = sred[0] + sred[1] + sred[2] + sred[3];
  __syncthreads();
  return v;
}

__global__ __launch_bounds__(256) void kred1(const float* __restrict__ partial,
                                             const float* __restrict__ pos,
                                             float* __restrict__ bsum,
                                             int* __restrict__ cnt,
                                             float* __restrict__ out) {
  const int r = blockIdx.x * 256 + threadIdx.x;
  float d = 0.f;
#pragma unroll 8
  for (int cbx = 0; cbx < 64; ++cbx) d += partial[(size_t)cbx * N2 + r];
  if (blockIdx.x >= 16) {   // rows >= 4096: add tail colsum slots 64..65
    d += partial[(size_t)64 * N2 + r];
    d += partial[(size_t)65 * N2 + r];
  }
  float v = logf(d);
  __shared__ float sred[4];
  __shared__ int lastFlag;
  v = blockReduce(v, sred);
  if (threadIdx.x == 0) {
    bsum[blockIdx.x] = v;
    __threadfence();
    lastFlag = (atomicAdd(cnt, 1) == 31);
  }
  __syncthreads();
  if (!lastFlag) return;
  __threadfence();
  float s = (threadIdx.x < 32) ? ((volatile float*)bsum)[threadIdx.x] : 0.f;
  float p = 0.f;
  for (int k = threadIdx.x; k < BSZ; k += 256) p += pos[k];
  s = blockReduce(s, sred);
  p = blockReduce(p, sred);
  if (threadIdx.x == 0) out[0] = (s - 2.0f * p / TEMPV) / (float)N2;
}

extern "C" void kernel_launch(void* const* d_in, const int* in_sizes, int n_in,
                              void* d_out, int out_size, void* d_ws, size_t ws_size,
                              hipStream_t stream) {
  const float* ei = (const float*)d_in[0];
  const float* ej = (const float*)d_in[1];
  char* ws = (char*)d_ws;
  unsigned char* reps4 = (unsigned char*)ws;                           // 4 MB fp4 [8192][512]
  float* partial = (float*)(ws + (size_t)4 * 1024 * 1024);             // 2.06 MB [66][8192]
  float* pos = (float*)(ws + (size_t)4 * 1024 * 1024 + 2176 * 1024);   // 16 KB [4096]
  float* bsum = (float*)(ws + (size_t)4 * 1024 * 1024 + 2176 * 1024 + 16384); // 128 B
  int* cnt = (int*)(ws + (size_t)4 * 1024 * 1024 + 2176 * 1024 + 16384 + 256);

  (void)hipFuncSetAttribute((const void*)kgemm3,
                            hipFuncAttributeMaxDynamicSharedMemorySize, 65536);

  knorm<<<BSZ, 256, 0, stream>>>(ei, ej, reps4, pos, cnt);
  kgemm3<<<576, 512, 65536, stream>>>(reps4, partial);
  kred1<<<32, 256, 0, stream>>>(partial, pos, bsum, cnt, (float*)d_out);
}